// Round 5
// baseline (311.489 us; speedup 1.0000x reference)
//
#include <hip/hip_runtime.h>

#define BATCH 256
#define NIN   1152
#define NOUT  10
#define DDIM  16
#define KPT   9    // NIN / 128 capsules per thread (each thread owns a d-quad)

// R8: register-resident routing logits. R5 skeleton (2560 blocks, 512 thr,
// KPT=9, natural dispatch stagger — best measured: 41.7us kernel) with the
// b/w LDS arrays eliminated:
//  - after the quad shfl_xor in agreement, all 4 lanes of a quad hold
//    bit-identical a_i -> b lives replicated in registers (b[9]/thread).
//  - max phase is pure-register (duplicates idempotent under fmax);
//    shuffle strides 32..4 only (2,1 mix only q-duplicates).
//  - exp/z/s fused into one register loop; z summed over DISTINCT capsules
//    (strides >=4 keep q fixed; column q=0 covers each i exactly once).
//  - ssum + red share one barrier; invZ applied by the t<16 combiners.
//  - agreement: pure-register b[k] += a; no trailing barrier (all LDS
//    overwrite hazards separated by >=2 barriers; verified per phase).
// Barriers: 19 -> 9 per item; both strided LDS loops + bsh/wsh gone.
// bar_lds (lgkm-only drain, proven numerics-safe in R7) lets the 9 u-loads
// stay in flight through round-0's pure-register softmax.

__device__ __forceinline__ void bar_lds() {
    asm volatile("s_waitcnt lgkmcnt(0)" ::: "memory");
    __builtin_amdgcn_s_barrier();
    asm volatile("" ::: "memory");
}

__global__ __launch_bounds__(512, 6)
void routing_kernel(const float* __restrict__ u_hat, float* __restrict__ out) {
    __shared__ float red[8][DDIM];    // per-wave partial s
    __shared__ float vsh[DDIM];       // raw s/Z (squash scale applied at use)
    __shared__ float smax[8];         // per-wave max
    __shared__ float ssum[8];         // per-wave distinct-sum of w

    const int t    = threadIdx.x;
    const int q    = t & 3;           // d-quad owner
    const int g    = t >> 2;          // 0..127 capsule group
    const int wave = t >> 6;          // 0..7
    const int lane = t & 63;

    // XCD-aware decode: 2560 blocks = 8 XCDs x 32 bb x 10 oo (bijective)
    const int x   = blockIdx.x;
    const int xcd = x & 7;
    const int j   = x >> 3;           // 0..319
    const int oo  = j % NOUT;
    const int bb  = xcd * 32 + j / NOUT;

    // u_hat flat index: ((bb*NIN + i)*NOUT + oo)*DDIM + d
    const float* base = u_hat + (size_t)bb * (NIN * NOUT * DDIM) + oo * DDIM + q * 4;

    float4 u[KPT];
#pragma unroll
    for (int k = 0; k < KPT; ++k) {
        const int i = g + 128 * k;
        u[k] = *reinterpret_cast<const float4*>(base + (size_t)i * (NOUT * DDIM));
    }

    float b[KPT];
#pragma unroll
    for (int k = 0; k < KPT; ++k) b[k] = 0.0f;

    float scale = 0.0f;
#pragma unroll 1
    for (int r = 0; r < 3; ++r) {
        // ---- softmax max: pure-register chain + q-preserving shuffle ----
        float m = b[0];
#pragma unroll
        for (int k = 1; k < KPT; ++k) m = fmaxf(m, b[k]);
        for (int off = 32; off >= 4; off >>= 1) m = fmaxf(m, __shfl_down(m, off));
        if (lane == 0) smax[wave] = m;
        bar_lds();                                               // barrier 1
        m = fmaxf(fmaxf(fmaxf(smax[0], smax[1]), fmaxf(smax[2], smax[3])),
                  fmaxf(fmaxf(smax[4], smax[5]), fmaxf(smax[6], smax[7])));

        // ---- fused w = exp(b-m), z partial, s partial (all registers) ----
        float z = 0.0f;
        float sx = 0.f, sy = 0.f, sz = 0.f, sw = 0.f;
#pragma unroll
        for (int k = 0; k < KPT; ++k) {
            const float wk = __expf(b[k] - m);
            z  += wk;
            sx += wk * u[k].x; sy += wk * u[k].y;
            sz += wk * u[k].z; sw += wk * u[k].w;
        }
        // q-preserving reduce: lane l<4 holds column-q=l over the wave's 16 g's
        // (z columns are bit-identical across q; each capsule counted once)
        for (int off = 32; off >= 4; off >>= 1) {
            z  += __shfl_down(z,  off);
            sx += __shfl_down(sx, off);
            sy += __shfl_down(sy, off);
            sz += __shfl_down(sz, off);
            sw += __shfl_down(sw, off);
        }
        if (lane == 0) ssum[wave] = z;
        if (lane < 4) {
            float* rp = &red[wave][lane * 4];
            rp[0] = sx; rp[1] = sy; rp[2] = sz; rp[3] = sw;
        }
        bar_lds();                                               // barrier 2
        if (t < DDIM) {
            const float invZ = 1.0f / (((ssum[0] + ssum[1]) + (ssum[2] + ssum[3])) +
                                       ((ssum[4] + ssum[5]) + (ssum[6] + ssum[7])));
            vsh[t] = (((red[0][t] + red[1][t]) + (red[2][t] + red[3][t])) +
                      ((red[4][t] + red[5][t]) + (red[6][t] + red[7][t]))) * invZ;
        }
        bar_lds();                                               // barrier 3

        // ---- squash scale (redundant per-thread, 16 broadcast LDS reads);
        //      deferred to use sites (identical rounding) ----
        float sqr = 0.0f;
#pragma unroll
        for (int d = 0; d < DDIM; ++d) { const float sv = vsh[d]; sqr += sv * sv; }
        scale = sqr / ((1.0f + sqr) * sqrtf(sqr + 1e-7f));

        if (r == 2) break;

        // ---- agreement: pure-register b update (quad lanes identical) ----
        const float vx = vsh[q * 4 + 0] * scale, vy = vsh[q * 4 + 1] * scale;
        const float vz = vsh[q * 4 + 2] * scale, vw = vsh[q * 4 + 3] * scale;
#pragma unroll
        for (int k = 0; k < KPT; ++k) {
            float a = u[k].x * vx + u[k].y * vy + u[k].z * vz + u[k].w * vw;
            a += __shfl_xor(a, 1);
            a += __shfl_xor(a, 2);
            b[k] += a;
        }
        // no trailing barrier: next phase is pure-register until the smax
        // write, and every LDS overwrite is >=2 barriers from its last read.
    }

    if (t < DDIM) {
        out[(size_t)(bb * NOUT + oo) * DDIM + t] = vsh[t] * scale;
    }
}

extern "C" void kernel_launch(void* const* d_in, const int* in_sizes, int n_in,
                              void* d_out, int out_size, void* d_ws, size_t ws_size,
                              hipStream_t stream) {
    const float* u_hat = (const float*)d_in[0];
    float* out = (float*)d_out;
    routing_kernel<<<dim3(BATCH * NOUT), dim3(512), 0, stream>>>(u_hat, out);
}

// Round 6
// 257.380 us; speedup vs baseline: 1.2102x; 1.2102x over previous
//
#include <hip/hip_runtime.h>

#define BATCH 256
#define NIN   1152
#define NOUT  10
#define DDIM  16
#define KPT   9    // NIN / 128 capsules per thread (each thread owns a d-quad)

// R9: R8 with the spill fixed. R8's rocprof showed VGPR_Count=40 +
// WRITE_SIZE=113MB (vs 0.16MB real output) + 134us: launch_bounds(512,6)
// capped VGPRs at ~84, and the fused exp/z/s loop (u[9]=36 + b[9]=9 + 5
// accumulators + temps live at once) exceeded it -> u spilled to scratch.
// Single-variable fix: (512,4) -> cap 128 VGPRs, no spill, 2 blocks/CU
// (same co-residency R3 had at 43us with MORE compute). Everything else
// bit-identical to R8 (absmax 7.6e-06 proved numerics exact):
//  - b logits quad-replicated in registers (agreement a_i identical in quad)
//  - pure-register softmax max (q-preserving shuffles, strides 32..4)
//  - fused w=exp(b-m) / z / s single pass over u
//  - ssum+red share one barrier; invZ applied by t<16 combiners
//  - 9 barriers per item (was 19), zero strided-LDS loops
//  - bar_lds: lgkm-only drain, keeps u-loads in flight through round 0

__device__ __forceinline__ void bar_lds() {
    asm volatile("s_waitcnt lgkmcnt(0)" ::: "memory");
    __builtin_amdgcn_s_barrier();
    asm volatile("" ::: "memory");
}

__global__ __launch_bounds__(512, 4)
void routing_kernel(const float* __restrict__ u_hat, float* __restrict__ out) {
    __shared__ float red[8][DDIM];    // per-wave partial s
    __shared__ float vsh[DDIM];       // raw s/Z (squash scale applied at use)
    __shared__ float smax[8];         // per-wave max
    __shared__ float ssum[8];         // per-wave distinct-sum of w

    const int t    = threadIdx.x;
    const int q    = t & 3;           // d-quad owner
    const int g    = t >> 2;          // 0..127 capsule group
    const int wave = t >> 6;          // 0..7
    const int lane = t & 63;

    // XCD-aware decode: 2560 blocks = 8 XCDs x 32 bb x 10 oo (bijective)
    const int x   = blockIdx.x;
    const int xcd = x & 7;
    const int j   = x >> 3;           // 0..319
    const int oo  = j % NOUT;
    const int bb  = xcd * 32 + j / NOUT;

    // u_hat flat index: ((bb*NIN + i)*NOUT + oo)*DDIM + d
    const float* base = u_hat + (size_t)bb * (NIN * NOUT * DDIM) + oo * DDIM + q * 4;

    float4 u[KPT];
#pragma unroll
    for (int k = 0; k < KPT; ++k) {
        const int i = g + 128 * k;
        u[k] = *reinterpret_cast<const float4*>(base + (size_t)i * (NOUT * DDIM));
    }

    float b[KPT];
#pragma unroll
    for (int k = 0; k < KPT; ++k) b[k] = 0.0f;

    float scale = 0.0f;
#pragma unroll 1
    for (int r = 0; r < 3; ++r) {
        // ---- softmax max: pure-register chain + q-preserving shuffle ----
        float m = b[0];
#pragma unroll
        for (int k = 1; k < KPT; ++k) m = fmaxf(m, b[k]);
        for (int off = 32; off >= 4; off >>= 1) m = fmaxf(m, __shfl_down(m, off));
        if (lane == 0) smax[wave] = m;
        bar_lds();                                               // barrier 1
        m = fmaxf(fmaxf(fmaxf(smax[0], smax[1]), fmaxf(smax[2], smax[3])),
                  fmaxf(fmaxf(smax[4], smax[5]), fmaxf(smax[6], smax[7])));

        // ---- fused w = exp(b-m), z partial, s partial (all registers) ----
        float z = 0.0f;
        float sx = 0.f, sy = 0.f, sz = 0.f, sw = 0.f;
#pragma unroll
        for (int k = 0; k < KPT; ++k) {
            const float wk = __expf(b[k] - m);
            z  += wk;
            sx += wk * u[k].x; sy += wk * u[k].y;
            sz += wk * u[k].z; sw += wk * u[k].w;
        }
        // q-preserving reduce: lane l<4 holds column-q=l over the wave's 16 g's
        // (z columns are bit-identical across q; each capsule counted once)
        for (int off = 32; off >= 4; off >>= 1) {
            z  += __shfl_down(z,  off);
            sx += __shfl_down(sx, off);
            sy += __shfl_down(sy, off);
            sz += __shfl_down(sz, off);
            sw += __shfl_down(sw, off);
        }
        if (lane == 0) ssum[wave] = z;
        if (lane < 4) {
            float* rp = &red[wave][lane * 4];
            rp[0] = sx; rp[1] = sy; rp[2] = sz; rp[3] = sw;
        }
        bar_lds();                                               // barrier 2
        if (t < DDIM) {
            const float invZ = 1.0f / (((ssum[0] + ssum[1]) + (ssum[2] + ssum[3])) +
                                       ((ssum[4] + ssum[5]) + (ssum[6] + ssum[7])));
            vsh[t] = (((red[0][t] + red[1][t]) + (red[2][t] + red[3][t])) +
                      ((red[4][t] + red[5][t]) + (red[6][t] + red[7][t]))) * invZ;
        }
        bar_lds();                                               // barrier 3

        // ---- squash scale (redundant per-thread, 16 broadcast LDS reads);
        //      deferred to use sites (identical rounding) ----
        float sqr = 0.0f;
#pragma unroll
        for (int d = 0; d < DDIM; ++d) { const float sv = vsh[d]; sqr += sv * sv; }
        scale = sqr / ((1.0f + sqr) * sqrtf(sqr + 1e-7f));

        if (r == 2) break;

        // ---- agreement: pure-register b update (quad lanes identical) ----
        const float vx = vsh[q * 4 + 0] * scale, vy = vsh[q * 4 + 1] * scale;
        const float vz = vsh[q * 4 + 2] * scale, vw = vsh[q * 4 + 3] * scale;
#pragma unroll
        for (int k = 0; k < KPT; ++k) {
            float a = u[k].x * vx + u[k].y * vy + u[k].z * vz + u[k].w * vw;
            a += __shfl_xor(a, 1);
            a += __shfl_xor(a, 2);
            b[k] += a;
        }
        // no trailing barrier: next phase is pure-register until the smax
        // write, and every LDS overwrite is >=2 barriers from its last read.
    }

    if (t < DDIM) {
        out[(size_t)(bb * NOUT + oo) * DDIM + t] = vsh[t] * scale;
    }
}

extern "C" void kernel_launch(void* const* d_in, const int* in_sizes, int n_in,
                              void* d_out, int out_size, void* d_ws, size_t ws_size,
                              hipStream_t stream) {
    const float* u_hat = (const float*)d_in[0];
    float* out = (float*)d_out;
    routing_kernel<<<dim3(BATCH * NOUT), dim3(512), 0, stream>>>(u_hat, out);
}

// Round 8
// 257.305 us; speedup vs baseline: 1.2106x; 1.0003x over previous
//
#include <hip/hip_runtime.h>

#define BATCH 256
#define NIN   1152
#define NOUT  10
#define DDIM  16
#define KPT   9    // NIN / 128 capsules per thread (each thread owns a d-quad)

// R10 (resubmit; previous bench died on container acquisition, no signal).
// R9 (register-resident b, fused exp/z/s, spill-free at (512,4),
// kernel ~37.4us) with the softmax-max phase DELETED. Softmax is shift-
// invariant for any uniform m; m=0 is uniform and overflow-safe here:
// |b| <= sum|u.v| with ||v||<1 (squash) and ||u||~4 -> |b| <~ 20,
// exp(b) <= 5e8, z <= 6e11 — comfortably inside float range. Round 0 is
// bit-identical (b=0 -> m was 0 anyway); rounds 1-2 differ only in
// rounding. Stateless (no replay-state hazard; the prior session's r=0-
// skip failure was its warm-LDS state trick, not used here).
// Deletes: 3 barriers/item (9 -> 6), register max chain, 12 shuffle-fmax,
// smax array + broadcast reads. Everything else identical to R9.
// Per-round barrier structure:
//   [reg: exp/z/s over u] -> shuffles -> write ssum/red -> bar A
//   [t<16: combine, write vsh] -> bar B
//   [all: read vsh, squash scale; agreement in registers]
// Cross-round LDS overwrite hazards each separated by a full barrier
// (writes of round r+1 to ssum/red are after B_r; to vsh after A_{r+1}).

__device__ __forceinline__ void bar_lds() {
    asm volatile("s_waitcnt lgkmcnt(0)" ::: "memory");
    __builtin_amdgcn_s_barrier();
    asm volatile("" ::: "memory");
}

__global__ __launch_bounds__(512, 4)
void routing_kernel(const float* __restrict__ u_hat, float* __restrict__ out) {
    __shared__ float red[8][DDIM];    // per-wave partial s
    __shared__ float vsh[DDIM];       // raw s/Z (squash scale applied at use)
    __shared__ float ssum[8];         // per-wave distinct-sum of w

    const int t    = threadIdx.x;
    const int q    = t & 3;           // d-quad owner
    const int g    = t >> 2;          // 0..127 capsule group
    const int wave = t >> 6;          // 0..7
    const int lane = t & 63;

    // XCD-aware decode: 2560 blocks = 8 XCDs x 32 bb x 10 oo (bijective)
    const int x   = blockIdx.x;
    const int xcd = x & 7;
    const int j   = x >> 3;           // 0..319
    const int oo  = j % NOUT;
    const int bb  = xcd * 32 + j / NOUT;

    // u_hat flat index: ((bb*NIN + i)*NOUT + oo)*DDIM + d
    const float* base = u_hat + (size_t)bb * (NIN * NOUT * DDIM) + oo * DDIM + q * 4;

    float4 u[KPT];
#pragma unroll
    for (int k = 0; k < KPT; ++k) {
        const int i = g + 128 * k;
        u[k] = *reinterpret_cast<const float4*>(base + (size_t)i * (NOUT * DDIM));
    }

    float b[KPT];
#pragma unroll
    for (int k = 0; k < KPT; ++k) b[k] = 0.0f;

    float scale = 0.0f;
#pragma unroll 1
    for (int r = 0; r < 3; ++r) {
        // ---- fused w = exp(b), z partial, s partial (all registers) ----
        float z = 0.0f;
        float sx = 0.f, sy = 0.f, sz = 0.f, sw = 0.f;
#pragma unroll
        for (int k = 0; k < KPT; ++k) {
            const float wk = __expf(b[k]);
            z  += wk;
            sx += wk * u[k].x; sy += wk * u[k].y;
            sz += wk * u[k].z; sw += wk * u[k].w;
        }
        // q-preserving reduce: lane l<4 holds column-q=l over the wave's 16 g's
        // (z columns are bit-identical across q; each capsule counted once)
        for (int off = 32; off >= 4; off >>= 1) {
            z  += __shfl_down(z,  off);
            sx += __shfl_down(sx, off);
            sy += __shfl_down(sy, off);
            sz += __shfl_down(sz, off);
            sw += __shfl_down(sw, off);
        }
        if (lane == 0) ssum[wave] = z;
        if (lane < 4) {
            float* rp = &red[wave][lane * 4];
            rp[0] = sx; rp[1] = sy; rp[2] = sz; rp[3] = sw;
        }
        bar_lds();                                               // barrier A
        if (t < DDIM) {
            const float invZ = 1.0f / (((ssum[0] + ssum[1]) + (ssum[2] + ssum[3])) +
                                       ((ssum[4] + ssum[5]) + (ssum[6] + ssum[7])));
            vsh[t] = (((red[0][t] + red[1][t]) + (red[2][t] + red[3][t])) +
                      ((red[4][t] + red[5][t]) + (red[6][t] + red[7][t]))) * invZ;
        }
        bar_lds();                                               // barrier B

        // ---- squash scale (redundant per-thread, 16 broadcast LDS reads);
        //      deferred to use sites (identical rounding) ----
        float sqr = 0.0f;
#pragma unroll
        for (int d = 0; d < DDIM; ++d) { const float sv = vsh[d]; sqr += sv * sv; }
        scale = sqr / ((1.0f + sqr) * sqrtf(sqr + 1e-7f));

        if (r == 2) break;

        // ---- agreement: pure-register b update (quad lanes identical) ----
        const float vx = vsh[q * 4 + 0] * scale, vy = vsh[q * 4 + 1] * scale;
        const float vz = vsh[q * 4 + 2] * scale, vw = vsh[q * 4 + 3] * scale;
#pragma unroll
        for (int k = 0; k < KPT; ++k) {
            float a = u[k].x * vx + u[k].y * vy + u[k].z * vz + u[k].w * vw;
            a += __shfl_xor(a, 1);
            a += __shfl_xor(a, 2);
            b[k] += a;
        }
        // no trailing barrier: next phase is pure-register until the
        // ssum/red writes, which sit behind barrier B of this round.
    }

    if (t < DDIM) {
        out[(size_t)(bb * NOUT + oo) * DDIM + t] = vsh[t] * scale;
    }
}

extern "C" void kernel_launch(void* const* d_in, const int* in_sizes, int n_in,
                              void* d_out, int out_size, void* d_ws, size_t ws_size,
                              hipStream_t stream) {
    const float* u_hat = (const float*)d_in[0];
    float* out = (float*)d_out;
    routing_kernel<<<dim3(BATCH * NOUT), dim3(512), 0, stream>>>(u_hat, out);
}